// Round 1
// baseline (72.073 us; speedup 1.0000x reference)
//
#include <hip/hip_runtime.h>

// SSIM loss, N=64 images, 1 channel, 384x384 f32, 7x7 box window, VALID -> 378x378.
// out = -mean(S) over all N*378*378 pixels.

constexpr int IND  = 384;   // input H = W
constexpr int OUTD = 378;   // output H = W (384 - 7 + 1)
constexpr int TH   = 32;    // output tile height
constexpr int TW   = 32;    // output tile width
constexpr int IT   = 38;    // input tile side (TH + 6)
constexpr int LDW  = 40;    // padded LDS row stride in floats (multiple of 4 for float4 alignment)
constexpr int TILES = 12;   // ceil(378/32)

using f32x4 = __attribute__((ext_vector_type(4))) float;
using f32x2 = __attribute__((ext_vector_type(2))) float;

__global__ __launch_bounds__(256)
void ssim_tile(const float* __restrict__ X, const float* __restrict__ Y,
               const float* __restrict__ MX, float* __restrict__ blocksum)
{
    __shared__ float sX[IT][LDW];
    __shared__ float sY[IT][LDW];
    __shared__ float vs[5][TH][LDW];   // vertical 7-tap sums of {x, y, xx, yy, xy}

    const int n   = blockIdx.z;
    const int tx  = blockIdx.x, ty = blockIdx.y;
    const int tid = threadIdx.x;
    const int row0 = ty * TH, col0 = tx * TW;
    const float q = 100000.0f;

    const float* __restrict__ Xn = X + (size_t)n * (IND * IND);
    const float* __restrict__ Yn = Y + (size_t)n * (IND * IND);

    // ---- stage input tile (38x38), clamped at edges (clamped rows/cols only feed masked outputs)
    for (int idx = tid; idx < IT * IT; idx += 256) {
        int r = idx / IT, c = idx - r * IT;
        int gr = row0 + r; if (gr > IND - 1) gr = IND - 1;
        int gc = col0 + c; if (gc > IND - 1) gc = IND - 1;
        sX[r][c] = Xn[gr * IND + gc] * q;
        sY[r][c] = Yn[gr * IND + gc] * q;
    }
    __syncthreads();

    // ---- vertical 7-tap sums, 4 columns at a time (10 float4 groups cover cols 0..39;
    //      cols 38..39 are garbage but never read by the horizontal stage: max col = 37)
    for (int idx = tid; idx < TH * 10; idx += 256) {
        int r = idx / 10, cg = idx - r * 10;
        f32x4 ax = 0.f, ay = 0.f, axx = 0.f, ayy = 0.f, axy = 0.f;
#pragma unroll
        for (int k = 0; k < 7; ++k) {
            f32x4 x = *(const f32x4*)&sX[r + k][cg * 4];
            f32x4 y = *(const f32x4*)&sY[r + k][cg * 4];
            ax += x; ay += y;
            axx += x * x; ayy += y * y; axy += x * y;
        }
        *(f32x4*)&vs[0][r][cg * 4] = ax;
        *(f32x4*)&vs[1][r][cg * 4] = ay;
        *(f32x4*)&vs[2][r][cg * 4] = axx;
        *(f32x4*)&vs[3][r][cg * 4] = ayy;
        *(f32x4*)&vs[4][r][cg * 4] = axy;
    }
    __syncthreads();

    // ---- horizontal 7-tap sums + SSIM formula; each thread makes 4 consecutive outputs
    const float m  = MX[n] * q;
    const float C1 = (0.01f * m) * (0.01f * m);
    const float C2 = (0.03f * m) * (0.03f * m);
    const float inv = 1.0f / 49.0f;
    const float cn  = 49.0f / 48.0f;   // COV_NORM

    const int r  = tid >> 3;          // 0..31
    const int cb = (tid & 7) * 4;     // 0,4,...,28

    float t[5][10];
#pragma unroll
    for (int qd = 0; qd < 5; ++qd) {
        f32x4 a = *(const f32x4*)&vs[qd][r][cb];
        f32x4 b = *(const f32x4*)&vs[qd][r][cb + 4];
        f32x2 c = *(const f32x2*)&vs[qd][r][cb + 8];
        t[qd][0] = a.x; t[qd][1] = a.y; t[qd][2] = a.z; t[qd][3] = a.w;
        t[qd][4] = b.x; t[qd][5] = b.y; t[qd][6] = b.z; t[qd][7] = b.w;
        t[qd][8] = c.x; t[qd][9] = c.y;
    }

    float partial = 0.f;
    const int orow = row0 + r;
#pragma unroll
    for (int j = 0; j < 4; ++j) {
        const int ocol = col0 + cb + j;
        if (orow < OUTD && ocol < OUTD) {
            float sx = 0.f, sy = 0.f, sxx = 0.f, syy = 0.f, sxy = 0.f;
#pragma unroll
            for (int k = 0; k < 7; ++k) {
                sx  += t[0][j + k];
                sy  += t[1][j + k];
                sxx += t[2][j + k];
                syy += t[3][j + k];
                sxy += t[4][j + k];
            }
            float ux = sx * inv, uy = sy * inv;
            float uxx = sxx * inv, uyy = syy * inv, uxy = sxy * inv;
            float vx  = cn * (uxx - ux * ux);
            float vy  = cn * (uyy - uy * uy);
            float vxy = cn * (uxy - ux * uy);
            float A1 = 2.f * ux * uy + C1;
            float A2 = 2.f * vxy + C2;
            float B1 = ux * ux + uy * uy + C1;
            float B2 = vx + vy + C2;
            partial += (A1 * A2) / (B1 * B2);
        }
    }

    // ---- block reduction -> one float per block (deterministic, no atomics)
#pragma unroll
    for (int off = 32; off; off >>= 1) partial += __shfl_down(partial, off);
    __shared__ float wsum[4];
    if ((tid & 63) == 0) wsum[tid >> 6] = partial;
    __syncthreads();
    if (tid == 0)
        blocksum[((size_t)n * TILES + ty) * TILES + tx] = wsum[0] + wsum[1] + wsum[2] + wsum[3];
}

__global__ __launch_bounds__(256)
void ssim_reduce(const float* __restrict__ blocksum, float* __restrict__ out,
                 int nblocks, float inv_npix)
{
    const int tid = threadIdx.x;
    float s = 0.f;
    for (int i = tid; i < nblocks; i += 256) s += blocksum[i];
#pragma unroll
    for (int off = 32; off; off >>= 1) s += __shfl_down(s, off);
    __shared__ float ws[4];
    if ((tid & 63) == 0) ws[tid >> 6] = s;
    __syncthreads();
    if (tid == 0) out[0] = -(ws[0] + ws[1] + ws[2] + ws[3]) * inv_npix;
}

extern "C" void kernel_launch(void* const* d_in, const int* in_sizes, int n_in,
                              void* d_out, int out_size, void* d_ws, size_t ws_size,
                              hipStream_t stream)
{
    const float* X  = (const float*)d_in[0];
    const float* Y  = (const float*)d_in[1];
    // d_in[2] = norm (unused by the reference), d_in[4] = w (= ones/49, baked in)
    const float* MX = (const float*)d_in[3];

    const int N = in_sizes[3];           // 64
    float* bs = (float*)d_ws;            // N*12*12 block sums = 36 KB

    dim3 grid(TILES, TILES, N);
    ssim_tile<<<grid, 256, 0, stream>>>(X, Y, MX, bs);

    const int nblocks = N * TILES * TILES;
    const float inv_npix = 1.0f / ((float)N * OUTD * OUTD);
    ssim_reduce<<<1, 256, 0, stream>>>(bs, (float*)d_out, nblocks, inv_npix);
}

// Round 2
// 60.407 us; speedup vs baseline: 1.1931x; 1.1931x over previous
//
#include <hip/hip_runtime.h>

// SSIM loss, N=64 images, 1 channel, 384x384 f32, 7x7 box window, VALID -> 378x378.
// out = -mean(S).
//
// Round-2 structure: no input staging (vertical moment sums read global directly;
// 7x row re-reads are L1 hits), q-scaling removed algebraically (S is invariant:
// A1,A2,B1,B2 each scale as q^2), sliding-window horizontal sums, LDS = vs only
// (25.6 KB -> 6 blocks/CU).

constexpr int IND   = 384;
constexpr int OUTD  = 378;
constexpr int TH    = 32;    // output tile height
constexpr int TW    = 32;    // output tile width
constexpr int LDW   = 40;    // vs row stride (floats); horizontal needs cols 0..37
constexpr int TILES = 12;

using f32x4 = __attribute__((ext_vector_type(4))) float;
using f32x2 = __attribute__((ext_vector_type(2))) float;

__global__ __launch_bounds__(256)
void ssim_tile(const float* __restrict__ X, const float* __restrict__ Y,
               const float* __restrict__ MX, float* __restrict__ blocksum)
{
    __shared__ float vs[5][TH][LDW];   // vertical 7-tap sums of {x, y, xx, yy, xy}

    const int n   = blockIdx.z;
    const int tx  = blockIdx.x, ty = blockIdx.y;
    const int tid = threadIdx.x;
    const int row0 = ty * TH, col0 = tx * TW;

    const float* __restrict__ Xn = X + (size_t)n * (IND * IND);
    const float* __restrict__ Yn = Y + (size_t)n * (IND * IND);

    // ---- vertical 7-tap moment sums, straight from global memory ----
    // 320 tasks: (r = 0..31) x (cg = 0..9), each produces 4 columns of vs.
    for (int idx = tid; idx < TH * 10; idx += 256) {
        const int r  = idx / 10;
        const int cg = idx - r * 10;
        const int gc = col0 + cg * 4;

        f32x4 ax = 0.f, ay = 0.f, axx = 0.f, ayy = 0.f, axy = 0.f;

        if (gc + 3 < IND) {
            if (row0 + r + 6 < IND) {
                // fast path: fully in-bounds
                const float* px = &Xn[(row0 + r) * IND + gc];
                const float* py = &Yn[(row0 + r) * IND + gc];
#pragma unroll
                for (int k = 0; k < 7; ++k) {
                    f32x4 x = *(const f32x4*)px;  px += IND;
                    f32x4 y = *(const f32x4*)py;  py += IND;
                    ax  += x;      ay  += y;
                    axx += x * x;  ayy += y * y;  axy += x * y;
                }
            } else {
                // bottom edge: clamp rows (feeds masked-out outputs only)
#pragma unroll
                for (int k = 0; k < 7; ++k) {
                    int gr = row0 + r + k; if (gr > IND - 1) gr = IND - 1;
                    f32x4 x = *(const f32x4*)&Xn[gr * IND + gc];
                    f32x4 y = *(const f32x4*)&Yn[gr * IND + gc];
                    ax  += x;      ay  += y;
                    axx += x * x;  ayy += y * y;  axy += x * y;
                }
            }
        } else {
            // right edge (tx==11, cg>=8): scalar column-clamped path
#pragma unroll
            for (int k = 0; k < 7; ++k) {
                int gr = row0 + r + k; if (gr > IND - 1) gr = IND - 1;
                const float* rx = &Xn[gr * IND];
                const float* ry = &Yn[gr * IND];
#pragma unroll
                for (int i = 0; i < 4; ++i) {
                    int c = gc + i; if (c > IND - 1) c = IND - 1;
                    float x = rx[c], y = ry[c];
                    ax[i]  += x;     ay[i]  += y;
                    axx[i] += x * x; ayy[i] += y * y; axy[i] += x * y;
                }
            }
        }

        *(f32x4*)&vs[0][r][cg * 4] = ax;
        *(f32x4*)&vs[1][r][cg * 4] = ay;
        *(f32x4*)&vs[2][r][cg * 4] = axx;
        *(f32x4*)&vs[3][r][cg * 4] = ayy;
        *(f32x4*)&vs[4][r][cg * 4] = axy;
    }
    __syncthreads();

    // ---- horizontal sliding-window 7-tap sums + SSIM formula ----
    const float m   = MX[n];                       // unscaled: S is q-invariant
    const float C1  = (0.01f * m) * (0.01f * m);
    const float C2  = (0.03f * m) * (0.03f * m);
    const float inv = 1.0f / 49.0f;
    const float cn  = 49.0f / 48.0f;

    const int r  = tid >> 3;          // 0..31
    const int cb = (tid & 7) * 4;     // 0,4,...,28

    float t0[10], t1[10], t2[10], t3[10], t4[10];
#define LOADT(T, Q)                                              \
    {                                                            \
        f32x4 a = *(const f32x4*)&vs[Q][r][cb];                  \
        f32x4 b = *(const f32x4*)&vs[Q][r][cb + 4];              \
        f32x2 c = *(const f32x2*)&vs[Q][r][cb + 8];              \
        T[0]=a.x; T[1]=a.y; T[2]=a.z; T[3]=a.w;                  \
        T[4]=b.x; T[5]=b.y; T[6]=b.z; T[7]=b.w;                  \
        T[8]=c.x; T[9]=c.y;                                      \
    }
    LOADT(t0, 0) LOADT(t1, 1) LOADT(t2, 2) LOADT(t3, 3) LOADT(t4, 4)
#undef LOADT

    float sx = 0.f, sy = 0.f, sxx = 0.f, syy = 0.f, sxy = 0.f;
#pragma unroll
    for (int k = 0; k < 7; ++k) {
        sx += t0[k]; sy += t1[k]; sxx += t2[k]; syy += t3[k]; sxy += t4[k];
    }

    float partial = 0.f;
    const int orow = row0 + r;
#pragma unroll
    for (int j = 0; j < 4; ++j) {
        if (j > 0) {   // slide the window
            sx  += t0[j + 6] - t0[j - 1];
            sy  += t1[j + 6] - t1[j - 1];
            sxx += t2[j + 6] - t2[j - 1];
            syy += t3[j + 6] - t3[j - 1];
            sxy += t4[j + 6] - t4[j - 1];
        }
        const int ocol = col0 + cb + j;
        if (orow < OUTD && ocol < OUTD) {
            float ux  = sx  * inv, uy  = sy  * inv;
            float uxx = sxx * inv, uyy = syy * inv, uxy = sxy * inv;
            float vx  = cn * (uxx - ux * ux);
            float vy  = cn * (uyy - uy * uy);
            float vxy = cn * (uxy - ux * uy);
            float A1 = 2.f * ux * uy + C1;
            float A2 = 2.f * vxy + C2;
            float B1 = ux * ux + uy * uy + C1;
            float B2 = vx + vy + C2;
            partial += (A1 * A2) / (B1 * B2);
        }
    }

    // ---- block reduction (deterministic, no atomics) ----
#pragma unroll
    for (int off = 32; off; off >>= 1) partial += __shfl_down(partial, off);
    __shared__ float wsum[4];
    if ((tid & 63) == 0) wsum[tid >> 6] = partial;
    __syncthreads();
    if (tid == 0)
        blocksum[((size_t)n * TILES + ty) * TILES + tx] = wsum[0] + wsum[1] + wsum[2] + wsum[3];
}

__global__ __launch_bounds__(256)
void ssim_reduce(const float* __restrict__ blocksum, float* __restrict__ out,
                 int nblocks, float inv_npix)
{
    const int tid = threadIdx.x;
    float s = 0.f;
    for (int i = tid; i < nblocks; i += 256) s += blocksum[i];
#pragma unroll
    for (int off = 32; off; off >>= 1) s += __shfl_down(s, off);
    __shared__ float ws[4];
    if ((tid & 63) == 0) ws[tid >> 6] = s;
    __syncthreads();
    if (tid == 0) out[0] = -(ws[0] + ws[1] + ws[2] + ws[3]) * inv_npix;
}

extern "C" void kernel_launch(void* const* d_in, const int* in_sizes, int n_in,
                              void* d_out, int out_size, void* d_ws, size_t ws_size,
                              hipStream_t stream)
{
    const float* X  = (const float*)d_in[0];
    const float* Y  = (const float*)d_in[1];
    // d_in[2] = norm (unused by the reference), d_in[4] = w (ones/49, baked in)
    const float* MX = (const float*)d_in[3];

    const int N = in_sizes[3];           // 64
    float* bs = (float*)d_ws;            // N*12*12 block sums = 36 KB

    dim3 grid(TILES, TILES, N);
    ssim_tile<<<grid, 256, 0, stream>>>(X, Y, MX, bs);

    const int nblocks = N * TILES * TILES;
    const float inv_npix = 1.0f / ((float)N * OUTD * OUTD);
    ssim_reduce<<<1, 256, 0, stream>>>(bs, (float*)d_out, nblocks, inv_npix);
}